// Round 5
// baseline (309.791 us; speedup 1.0000x reference)
//
#include <hip/hip_runtime.h>
#include <math.h>

#define LQ 1024
#define RS 512          // H*E floats between consecutive l in [B,L,H,E]
#define PJ 26           // padded j-stride for P
#define NP 32
#define ASCALE 0.18033688f   // 0.125 * log2(e)  -> softmax computed in base-2 domain

typedef __attribute__((ext_vector_type(4))) float f32x4;
typedef __attribute__((ext_vector_type(8))) short short8x;
typedef __attribute__((ext_vector_type(4))) short short4x;

__device__ __forceinline__ unsigned short f2bf(float f) {
  unsigned u = __float_as_uint(f);
  u += 0x7fffu + ((u >> 16) & 1u);
  return (unsigned short)(u >> 16);
}
// swizzled LDS byte address for [rows][64 bf16], row stride 128B
__device__ __forceinline__ int swz(int row, int bc) {
  return row * 128 + (bc ^ ((row & 7) << 4));
}
// VT variant: spreads banks when write-rows differ by 4
__device__ __forceinline__ int swzVT(int row, int bc) {
  return row * 128 + (bc ^ ((((row >> 3) ^ row) & 7) << 4));
}

// P[pair, l, j] = (scale*log2e) * dot(x[b,l,h,:], rel_k_table[j,:])
__global__ __launch_bounds__(256) void k_relproj(const float* __restrict__ x,
                                                 const float* __restrict__ relk,
                                                 float* __restrict__ P) {
  __shared__ float rk[25][68];
  __shared__ float xs[64][68];
  const int tid = threadIdx.x;
  const int pair = blockIdx.y, l0 = blockIdx.x * 64;
  const int b = pair >> 3, h = pair & 7;
  for (int i = tid; i < 25 * 64; i += 256) rk[i >> 6][i & 63] = relk[i] * ASCALE;
  const int row = tid >> 2, q = tid & 3;
  const float* xr = x + (size_t)b * 524288 + (size_t)(l0 + row) * RS + h * 64 + q * 16;
#pragma unroll
  for (int i = 0; i < 4; ++i) {
    float4 a = *(const float4*)(xr + i * 4);
    xs[row][q * 16 + i * 4 + 0] = a.x; xs[row][q * 16 + i * 4 + 1] = a.y;
    xs[row][q * 16 + i * 4 + 2] = a.z; xs[row][q * 16 + i * 4 + 3] = a.w;
  }
  __syncthreads();
  float* Pr = P + ((size_t)pair * LQ + l0 + row) * PJ;
  for (int j = q; j < 25; j += 4) {
    float acc = 0.f;
#pragma unroll
    for (int e = 0; e < 64; ++e) acc += xs[row][e] * rk[j][e];
    Pr[j] = acc;
  }
}

// One kernel, both modes (mode = group>>5 after XCD remap).
// MODE 0: A=x*ASC, B=y, V=v_y, tab=rel_vy, bias=P[l][j]
// MODE 1: A=y*ASC, B=x, V=v_x, tab=rel_vx, bias=P[s][24-j]; j=clip(s-l,-12,12)+12
__global__ __launch_bounds__(256, 3) void k_fused(
    const float* __restrict__ x, const float* __restrict__ y,
    const float* __restrict__ vx, const float* __restrict__ vy,
    const float* __restrict__ relvx, const float* __restrict__ relvy,
    const float* __restrict__ P_g, float* __restrict__ out_g) {
  __shared__ __align__(16) char U[8192];       // A-stage -> per-wave E tiles -> tab
  __shared__ __align__(16) char Bb[2][8192];
  __shared__ __align__(16) char Vb[2][8192];
  __shared__ float W[64 * PJ];

  const int tid = threadIdx.x;
  // bijective remap: p = m*64 + g  => the 16 blocks of group g share p%8 (same XCD)
  const int p = blockIdx.x;
  const int g = p & 63, bx = p >> 6;
  const int pair = g & 31, mode = g >> 5;
  const int b = pair >> 3, h = pair & 7;
  const int l0 = bx * 64;

  const float* Af = mode ? y : x;
  const float* Bl = mode ? x : y;
  const float* Vv = mode ? vx : vy;
  const float* tb = mode ? relvx : relvy;
  float* outp = out_g + (mode ? 2097152 : 0);

  const float* abase = Af + (size_t)b * 524288 + h * 64;
  const float* bbase = Bl + (size_t)b * 524288 + h * 64;
  const float* vbase = Vv + (size_t)b * 524288 + h * 64;
  const float* Pbase = P_g + (size_t)pair * LQ * PJ;
  float* outb = outp + (size_t)b * 524288 + h * 64;

  const int browA = tid >> 2, bqA = tid & 3;   // A/B staging mapping
  const int vsb = tid >> 4, vdb = tid & 15;    // VT staging mapping

  // ---- prologue: stage A(U), B0, VT0; zero W ----
  {
    const float* s = abase + (size_t)(l0 + browA) * RS + bqA * 16;
#pragma unroll
    for (int hh = 0; hh < 2; ++hh) {
      float4 a = *(const float4*)(s + hh * 8);
      float4 c = *(const float4*)(s + hh * 8 + 4);
      short8x v;
      v[0]=(short)f2bf(a.x*ASCALE); v[1]=(short)f2bf(a.y*ASCALE);
      v[2]=(short)f2bf(a.z*ASCALE); v[3]=(short)f2bf(a.w*ASCALE);
      v[4]=(short)f2bf(c.x*ASCALE); v[5]=(short)f2bf(c.y*ASCALE);
      v[6]=(short)f2bf(c.z*ASCALE); v[7]=(short)f2bf(c.w*ASCALE);
      *(short8x*)(U + swz(browA, bqA * 32 + hh * 16)) = v;
    }
    const float* sb2 = bbase + (size_t)browA * RS + bqA * 16;
#pragma unroll
    for (int hh = 0; hh < 2; ++hh) {
      float4 a = *(const float4*)(sb2 + hh * 8);
      float4 c = *(const float4*)(sb2 + hh * 8 + 4);
      short8x v;
      v[0]=(short)f2bf(a.x); v[1]=(short)f2bf(a.y); v[2]=(short)f2bf(a.z); v[3]=(short)f2bf(a.w);
      v[4]=(short)f2bf(c.x); v[5]=(short)f2bf(c.y); v[6]=(short)f2bf(c.z); v[7]=(short)f2bf(c.w);
      *(short8x*)(Bb[0] + swz(browA, bqA * 32 + hh * 16)) = v;
    }
    const float* sv = vbase + (size_t)vsb * 4 * RS + vdb * 4;
    float4 r0 = *(const float4*)(sv);
    float4 r1 = *(const float4*)(sv + RS);
    float4 r2 = *(const float4*)(sv + 2 * RS);
    float4 r3 = *(const float4*)(sv + 3 * RS);
    short4x v;
    v[0]=(short)f2bf(r0.x); v[1]=(short)f2bf(r1.x); v[2]=(short)f2bf(r2.x); v[3]=(short)f2bf(r3.x);
    *(short4x*)(Vb[0] + swzVT(vdb * 4 + 0, vsb * 8)) = v;
    v[0]=(short)f2bf(r0.y); v[1]=(short)f2bf(r1.y); v[2]=(short)f2bf(r2.y); v[3]=(short)f2bf(r3.y);
    *(short4x*)(Vb[0] + swzVT(vdb * 4 + 1, vsb * 8)) = v;
    v[0]=(short)f2bf(r0.z); v[1]=(short)f2bf(r1.z); v[2]=(short)f2bf(r2.z); v[3]=(short)f2bf(r3.z);
    *(short4x*)(Vb[0] + swzVT(vdb * 4 + 2, vsb * 8)) = v;
    v[0]=(short)f2bf(r0.w); v[1]=(short)f2bf(r1.w); v[2]=(short)f2bf(r2.w); v[3]=(short)f2bf(r3.w);
    *(short4x*)(Vb[0] + swzVT(vdb * 4 + 3, vsb * 8)) = v;
  }
  for (int i = tid; i < 64 * PJ; i += 256) W[i] = 0.f;
  __syncthreads();

  const int lane = tid & 63, wv = tid >> 6;
  const int col16 = lane & 15, rg = lane >> 4;
  char* ea = U + wv * 2048;   // per-wave E tile (same bytes as this wave's A rows)

  // A fragments (own-wave region; program-order safe vs later E-writes)
  short8x af0 = *(const short8x*)(U + swz(wv * 16 + col16, rg * 16));
  short8x af1 = *(const short8x*)(U + swz(wv * 16 + col16, 64 + rg * 16));

  f32x4 accO[4];
  float rowsum[4], wl[4], wr[4];
  const f32x4 z4 = {0.f, 0.f, 0.f, 0.f};
#pragma unroll
  for (int r = 0; r < 4; ++r) { rowsum[r] = 0.f; wl[r] = 0.f; wr[r] = 0.f; }
#pragma unroll
  for (int dt = 0; dt < 4; ++dt) accO[dt] = z4;

  for (int t = 0; t < 16; ++t) {
    const int cb = t & 1, nb = cb ^ 1;
    const int rel0 = t * 64 - l0;
    const bool band = (rel0 >= -74 && rel0 <= 74);

    // ---- bias loads FIRST (global row = l0 + local row; global col = t*64 + local col) ----
    float biasf[4];
    float biasb[4][4];
    if (!band) {
      const bool right = rel0 > 0;
      if (mode == 0) {
#pragma unroll
        for (int r = 0; r < 4; ++r)
          biasf[r] = Pbase[(size_t)(l0 + wv * 16 + rg * 4 + r) * PJ + (right ? 24 : 0)];
      } else {
#pragma unroll
        for (int ct = 0; ct < 4; ++ct)
          biasf[ct] = Pbase[(size_t)(t * 64 + ct * 16 + col16) * PJ + (right ? 0 : 24)];
      }
    } else {
#pragma unroll
      for (int ct = 0; ct < 4; ++ct) {
#pragma unroll
        for (int r = 0; r < 4; ++r) {
          const int c = ct * 16 + col16, row = wv * 16 + rg * 4 + r;
          int d = rel0 + c - row;
          int j = (d < -12 ? -12 : (d > 12 ? 12 : d)) + 12;
          biasb[ct][r] = (mode == 0) ? Pbase[(size_t)(l0 + row) * PJ + j]
                                     : Pbase[(size_t)(t * 64 + c) * PJ + (24 - j)];
        }
      }
    }

    // ---- B prefetch (issue; consumed after QK) ----
    float4 pb[4];
    if (t < 15) {
      const float* s = bbase + (size_t)((t + 1) * 64 + browA) * RS + bqA * 16;
#pragma unroll
      for (int i = 0; i < 4; ++i) pb[i] = *(const float4*)(s + i * 4);
    }

    // ---- QK: T = A·B^T (16x64 strip/wave) ----
    f32x4 accS[4];
    const char* bB = Bb[cb];
    __builtin_amdgcn_s_setprio(1);
#pragma unroll
    for (int ct = 0; ct < 4; ++ct) {
      short8x bf0 = *(const short8x*)(bB + swz(ct * 16 + col16, rg * 16));
      short8x bf1 = *(const short8x*)(bB + swz(ct * 16 + col16, 64 + rg * 16));
      f32x4 tacc = __builtin_amdgcn_mfma_f32_16x16x32_bf16(af0, bf0, z4, 0, 0, 0);
      accS[ct] = __builtin_amdgcn_mfma_f32_16x16x32_bf16(af1, bf1, tacc, 0, 0, 0);
    }
    __builtin_amdgcn_s_setprio(0);

    // ---- write staged B -> nb (other buffer; no race with cb readers) ----
    if (t < 15) {
      short8x v;
      v[0]=(short)f2bf(pb[0].x); v[1]=(short)f2bf(pb[0].y); v[2]=(short)f2bf(pb[0].z); v[3]=(short)f2bf(pb[0].w);
      v[4]=(short)f2bf(pb[1].x); v[5]=(short)f2bf(pb[1].y); v[6]=(short)f2bf(pb[1].z); v[7]=(short)f2bf(pb[1].w);
      *(short8x*)(Bb[nb] + swz(browA, bqA * 32)) = v;
      v[0]=(short)f2bf(pb[2].x); v[1]=(short)f2bf(pb[2].y); v[2]=(short)f2bf(pb[2].z); v[3]=(short)f2bf(pb[2].w);
      v[4]=(short)f2bf(pb[3].x); v[5]=(short)f2bf(pb[3].y); v[6]=(short)f2bf(pb[3].z); v[7]=(short)f2bf(pb[3].w);
      *(short8x*)(Bb[nb] + swz(browA, bqA * 32 + 16)) = v;
    }

    // ---- VT prefetch (issue; consumed after AV — hidden under epilogue+AV) ----
    float4 pv[4];
    if (t < 15) {
      const float* s = vbase + (size_t)((t + 1) * 64 + vsb * 4) * RS + vdb * 4;
#pragma unroll
      for (int k = 0; k < 4; ++k) pv[k] = *(const float4*)(s + (size_t)k * RS);
    }

    // ---- epilogue: bias, exp2, rowsum, rel-V buckets, E -> own-wave LDS ----
    if (!band) {
      const bool right = rel0 > 0;
#pragma unroll
      for (int ct = 0; ct < 4; ++ct) {
#pragma unroll
        for (int r = 0; r < 4; ++r) {
          float bias = mode ? biasf[ct] : biasf[r];
          float e = __builtin_exp2f(accS[ct][r] + bias);
          rowsum[r] += e;
          if (right) wr[r] += e; else wl[r] += e;
          *(short*)(ea + swz(rg * 4 + r, (ct * 16 + col16) * 2)) = (short)f2bf(e);
        }
      }
    } else {
#pragma unroll
      for (int ct = 0; ct < 4; ++ct) {
#pragma unroll
        for (int r = 0; r < 4; ++r) {
          const int row = wv * 16 + rg * 4 + r;
          const int d = rel0 + ct * 16 + col16 - row;
          float e = __builtin_exp2f(accS[ct][r] + biasb[ct][r]);
          rowsum[r] += e;
          if (d <= -12) wl[r] += e;
          else if (d >= 12) wr[r] += e;
          else W[row * PJ + (d + 12)] = e;   // unique (row,j), j in [1,23]
          *(short*)(ea + swz(rg * 4 + r, (ct * 16 + col16) * 2)) = (short)f2bf(e);
        }
      }
    }

    // ---- wave-local E handoff (EA is per-wave; rule #18 pattern) ----
    __builtin_amdgcn_sched_barrier(0);
    asm volatile("s_waitcnt lgkmcnt(0)" ::: "memory");
    __builtin_amdgcn_sched_barrier(0);

    // ---- AV: O += E·V ----
    const char* vB = Vb[cb];
    short8x ef0 = *(const short8x*)(ea + swz(col16, rg * 16));
    short8x ef1 = *(const short8x*)(ea + swz(col16, 64 + rg * 16));
    __builtin_amdgcn_s_setprio(1);
#pragma unroll
    for (int dt = 0; dt < 4; ++dt) {
      short8x v0 = *(const short8x*)(vB + swzVT(dt * 16 + col16, rg * 16));
      short8x v1 = *(const short8x*)(vB + swzVT(dt * 16 + col16, 64 + rg * 16));
      f32x4 tacc = __builtin_amdgcn_mfma_f32_16x16x32_bf16(ef0, v0, accO[dt], 0, 0, 0);
      accO[dt] = __builtin_amdgcn_mfma_f32_16x16x32_bf16(ef1, v1, tacc, 0, 0, 0);
    }
    __builtin_amdgcn_s_setprio(0);

    // ---- write staged VT -> nb ----
    if (t < 15) {
      short4x w4;
      w4[0]=(short)f2bf(pv[0].x); w4[1]=(short)f2bf(pv[1].x); w4[2]=(short)f2bf(pv[2].x); w4[3]=(short)f2bf(pv[3].x);
      *(short4x*)(Vb[nb] + swzVT(vdb * 4 + 0, vsb * 8)) = w4;
      w4[0]=(short)f2bf(pv[0].y); w4[1]=(short)f2bf(pv[1].y); w4[2]=(short)f2bf(pv[2].y); w4[3]=(short)f2bf(pv[3].y);
      *(short4x*)(Vb[nb] + swzVT(vdb * 4 + 1, vsb * 8)) = w4;
      w4[0]=(short)f2bf(pv[0].z); w4[1]=(short)f2bf(pv[1].z); w4[2]=(short)f2bf(pv[2].z); w4[3]=(short)f2bf(pv[3].z);
      *(short4x*)(Vb[nb] + swzVT(vdb * 4 + 2, vsb * 8)) = w4;
      w4[0]=(short)f2bf(pv[0].w); w4[1]=(short)f2bf(pv[1].w); w4[2]=(short)f2bf(pv[2].w); w4[3]=(short)f2bf(pv[3].w);
      *(short4x*)(Vb[nb] + swzVT(vdb * 4 + 3, vsb * 8)) = w4;
    }
    __syncthreads();  // single barrier per step
  }

  // ---- tab into U (E region dead now) ----
  float* tabf = (float*)U;
  for (int i = tid; i < 25 * 64; i += 256) tabf[i] = tb[i];
  __syncthreads();

  // ---- reduce stats, rel-V, normalize, store ----
#pragma unroll
  for (int r = 0; r < 4; ++r) {
#pragma unroll
    for (int m = 1; m < 16; m <<= 1) {
      rowsum[r] += __shfl_xor(rowsum[r], m);
      wl[r] += __shfl_xor(wl[r], m);
      wr[r] += __shfl_xor(wr[r], m);
    }
  }
  float inv[4];
#pragma unroll
  for (int r = 0; r < 4; ++r) inv[r] = 1.f / rowsum[r];

#pragma unroll
  for (int dt = 0; dt < 4; ++dt) {
#pragma unroll
    for (int r = 0; r < 4; ++r) {
      const int row = wv * 16 + rg * 4 + r;
      const int dd = dt * 16 + col16;
      float vr = wl[r] * tabf[dd] + wr[r] * tabf[24 * 64 + dd];
#pragma unroll
      for (int j = 1; j < 24; ++j) vr += W[row * PJ + j] * tabf[j * 64 + dd];
      outb[(size_t)(l0 + row) * RS + dd] = (accO[dt][r] + vr) * inv[r];
    }
  }
}

extern "C" void kernel_launch(void* const* d_in, const int* in_sizes, int n_in,
                              void* d_out, int out_size, void* d_ws, size_t ws_size,
                              hipStream_t stream) {
  const float* x = (const float*)d_in[0];
  const float* y = (const float*)d_in[1];
  const float* vx = (const float*)d_in[2];
  const float* vy = (const float*)d_in[3];
  const float* relk = (const float*)d_in[4];
  const float* relvx = (const float*)d_in[5];
  const float* relvy = (const float*)d_in[6];
  float* out = (float*)d_out;

  float* P = (float*)d_ws;  // [32][1024][PJ] f32 = 3.4 MB

  k_relproj<<<dim3(16, NP), 256, 0, stream>>>(x, relk, P);
  k_fused<<<dim3(1024), 256, 0, stream>>>(x, y, vx, vy, relvx, relvy, P, out);
}

// Round 6
// 137.784 us; speedup vs baseline: 2.2484x; 2.2484x over previous
//
#include <hip/hip_runtime.h>
#include <math.h>

#define LQ 1024
#define RS 512          // H*E floats between consecutive l in [B,L,H,E]
#define PJ 26           // padded j-stride for P
#define NP 32
#define ASCALE 0.18033688f   // 0.125 * log2(e)  -> softmax computed in base-2 domain

typedef __attribute__((ext_vector_type(4))) float f32x4;
typedef __attribute__((ext_vector_type(8))) short short8x;
typedef __attribute__((ext_vector_type(4))) short short4x;

__device__ __forceinline__ unsigned short f2bf(float f) {
  unsigned u = __float_as_uint(f);
  u += 0x7fffu + ((u >> 16) & 1u);
  return (unsigned short)(u >> 16);
}
// swizzled LDS byte address for [rows][64 bf16], row stride 128B
__device__ __forceinline__ int swz(int row, int bc) {
  return row * 128 + (bc ^ ((row & 7) << 4));
}
// VT variant: spreads banks when write-rows differ by 4
__device__ __forceinline__ int swzVT(int row, int bc) {
  return row * 128 + (bc ^ ((((row >> 3) ^ row) & 7) << 4));
}

// P[pair, l, j] = (scale*log2e) * dot(x[b,l,h,:], rel_k_table[j,:])
__global__ __launch_bounds__(256) void k_relproj(const float* __restrict__ x,
                                                 const float* __restrict__ relk,
                                                 float* __restrict__ P) {
  __shared__ float rk[25][68];
  __shared__ float xs[64][68];
  const int tid = threadIdx.x;
  const int pair = blockIdx.y, l0 = blockIdx.x * 64;
  const int b = pair >> 3, h = pair & 7;
  for (int i = tid; i < 25 * 64; i += 256) rk[i >> 6][i & 63] = relk[i] * ASCALE;
  const int row = tid >> 2, q = tid & 3;
  const float* xr = x + (size_t)b * 524288 + (size_t)(l0 + row) * RS + h * 64 + q * 16;
#pragma unroll
  for (int i = 0; i < 4; ++i) {
    float4 a = *(const float4*)(xr + i * 4);
    xs[row][q * 16 + i * 4 + 0] = a.x; xs[row][q * 16 + i * 4 + 1] = a.y;
    xs[row][q * 16 + i * 4 + 2] = a.z; xs[row][q * 16 + i * 4 + 3] = a.w;
  }
  __syncthreads();
  float* Pr = P + ((size_t)pair * LQ + l0 + row) * PJ;
  for (int j = q; j < 25; j += 4) {
    float acc = 0.f;
#pragma unroll
    for (int e = 0; e < 64; ++e) acc += xs[row][e] * rk[j][e];
    Pr[j] = acc;
  }
}

// One kernel, both modes (mode = group>>5 after XCD remap).
// MODE 0: A=x*ASC, B=y, V=v_y, tab=rel_vy, bias=P[l][j]
// MODE 1: A=y*ASC, B=x, V=v_x, tab=rel_vx, bias=P[s][24-j]; j=clip(s-l,-12,12)+12
__global__ __launch_bounds__(256, 2) void k_fused(
    const float* __restrict__ x, const float* __restrict__ y,
    const float* __restrict__ vx, const float* __restrict__ vy,
    const float* __restrict__ relvx, const float* __restrict__ relvy,
    const float* __restrict__ P_g, float* __restrict__ out_g) {
  __shared__ __align__(16) char U[8192];       // A-stage -> per-wave E tiles -> tab
  __shared__ __align__(16) char Bb[2][8192];
  __shared__ __align__(16) char Vb[2][8192];
  __shared__ float W[64 * PJ];

  const int tid = threadIdx.x;
  // bijective remap: p = m*64 + g  => the 16 blocks of group g share p%8 (same XCD)
  const int p = blockIdx.x;
  const int g = p & 63, bx = p >> 6;
  const int pair = g & 31, mode = g >> 5;
  const int b = pair >> 3, h = pair & 7;
  const int l0 = bx * 64;

  const float* Af = mode ? y : x;
  const float* Bl = mode ? x : y;
  const float* Vv = mode ? vx : vy;
  const float* tb = mode ? relvx : relvy;
  float* outp = out_g + (mode ? 2097152 : 0);

  const float* abase = Af + (size_t)b * 524288 + h * 64;
  const float* bbase = Bl + (size_t)b * 524288 + h * 64;
  const float* vbase = Vv + (size_t)b * 524288 + h * 64;
  const float* Pbase = P_g + (size_t)pair * LQ * PJ;
  float* outb = outp + (size_t)b * 524288 + h * 64;

  const int browA = tid >> 2, bqA = tid & 3;   // A/B staging mapping
  const int vsb = tid >> 4, vdb = tid & 15;    // VT staging mapping

  // ---- prologue: stage A(U), B0, VT0; zero W ----
  {
    const float* s = abase + (size_t)(l0 + browA) * RS + bqA * 16;
#pragma unroll
    for (int hh = 0; hh < 2; ++hh) {
      float4 a = *(const float4*)(s + hh * 8);
      float4 c = *(const float4*)(s + hh * 8 + 4);
      short8x v;
      v[0]=(short)f2bf(a.x*ASCALE); v[1]=(short)f2bf(a.y*ASCALE);
      v[2]=(short)f2bf(a.z*ASCALE); v[3]=(short)f2bf(a.w*ASCALE);
      v[4]=(short)f2bf(c.x*ASCALE); v[5]=(short)f2bf(c.y*ASCALE);
      v[6]=(short)f2bf(c.z*ASCALE); v[7]=(short)f2bf(c.w*ASCALE);
      *(short8x*)(U + swz(browA, bqA * 32 + hh * 16)) = v;
    }
    const float* sb2 = bbase + (size_t)browA * RS + bqA * 16;
#pragma unroll
    for (int hh = 0; hh < 2; ++hh) {
      float4 a = *(const float4*)(sb2 + hh * 8);
      float4 c = *(const float4*)(sb2 + hh * 8 + 4);
      short8x v;
      v[0]=(short)f2bf(a.x); v[1]=(short)f2bf(a.y); v[2]=(short)f2bf(a.z); v[3]=(short)f2bf(a.w);
      v[4]=(short)f2bf(c.x); v[5]=(short)f2bf(c.y); v[6]=(short)f2bf(c.z); v[7]=(short)f2bf(c.w);
      *(short8x*)(Bb[0] + swz(browA, bqA * 32 + hh * 16)) = v;
    }
    const float* sv = vbase + (size_t)vsb * 4 * RS + vdb * 4;
    float4 r0 = *(const float4*)(sv);
    float4 r1 = *(const float4*)(sv + RS);
    float4 r2 = *(const float4*)(sv + 2 * RS);
    float4 r3 = *(const float4*)(sv + 3 * RS);
    short4x v;
    v[0]=(short)f2bf(r0.x); v[1]=(short)f2bf(r1.x); v[2]=(short)f2bf(r2.x); v[3]=(short)f2bf(r3.x);
    *(short4x*)(Vb[0] + swzVT(vdb * 4 + 0, vsb * 8)) = v;
    v[0]=(short)f2bf(r0.y); v[1]=(short)f2bf(r1.y); v[2]=(short)f2bf(r2.y); v[3]=(short)f2bf(r3.y);
    *(short4x*)(Vb[0] + swzVT(vdb * 4 + 1, vsb * 8)) = v;
    v[0]=(short)f2bf(r0.z); v[1]=(short)f2bf(r1.z); v[2]=(short)f2bf(r2.z); v[3]=(short)f2bf(r3.z);
    *(short4x*)(Vb[0] + swzVT(vdb * 4 + 2, vsb * 8)) = v;
    v[0]=(short)f2bf(r0.w); v[1]=(short)f2bf(r1.w); v[2]=(short)f2bf(r2.w); v[3]=(short)f2bf(r3.w);
    *(short4x*)(Vb[0] + swzVT(vdb * 4 + 3, vsb * 8)) = v;
  }
  for (int i = tid; i < 64 * PJ; i += 256) W[i] = 0.f;
  __syncthreads();

  const int lane = tid & 63, wv = tid >> 6;
  const int col16 = lane & 15, rg = lane >> 4;
  char* ea = U + wv * 2048;   // per-wave E tile (same bytes as this wave's A rows)

  // A fragments (own-wave region; program-order safe vs later E-writes)
  short8x af0 = *(const short8x*)(U + swz(wv * 16 + col16, rg * 16));
  short8x af1 = *(const short8x*)(U + swz(wv * 16 + col16, 64 + rg * 16));

  f32x4 accO[4];
  float rowsum[4], wl[4], wr[4];
  const f32x4 z4 = {0.f, 0.f, 0.f, 0.f};
#pragma unroll
  for (int r = 0; r < 4; ++r) { rowsum[r] = 0.f; wl[r] = 0.f; wr[r] = 0.f; }
#pragma unroll
  for (int dt = 0; dt < 4; ++dt) accO[dt] = z4;

  for (int t = 0; t < 16; ++t) {
    const int cb = t & 1, nb = cb ^ 1;
    const int rel0 = t * 64 - l0;
    const bool band = (rel0 >= -74 && rel0 <= 74);

    // ---- bias loads FIRST (global row = l0 + local row; global col = t*64 + local col) ----
    float biasf[4];
    float biasb[4][4];
    if (!band) {
      const bool right = rel0 > 0;
      if (mode == 0) {
#pragma unroll
        for (int r = 0; r < 4; ++r)
          biasf[r] = Pbase[(size_t)(l0 + wv * 16 + rg * 4 + r) * PJ + (right ? 24 : 0)];
      } else {
#pragma unroll
        for (int ct = 0; ct < 4; ++ct)
          biasf[ct] = Pbase[(size_t)(t * 64 + ct * 16 + col16) * PJ + (right ? 0 : 24)];
      }
    } else {
#pragma unroll
      for (int ct = 0; ct < 4; ++ct) {
#pragma unroll
        for (int r = 0; r < 4; ++r) {
          const int c = ct * 16 + col16, row = wv * 16 + rg * 4 + r;
          int d = rel0 + c - row;
          int j = (d < -12 ? -12 : (d > 12 ? 12 : d)) + 12;
          biasb[ct][r] = (mode == 0) ? Pbase[(size_t)(l0 + row) * PJ + j]
                                     : Pbase[(size_t)(t * 64 + c) * PJ + (24 - j)];
        }
      }
    }

    // ---- B prefetch (issue; consumed after QK) ----
    float4 pb[4];
    if (t < 15) {
      const float* s = bbase + (size_t)((t + 1) * 64 + browA) * RS + bqA * 16;
#pragma unroll
      for (int i = 0; i < 4; ++i) pb[i] = *(const float4*)(s + i * 4);
    }

    // ---- QK: T = A·B^T (16x64 strip/wave) ----
    f32x4 accS[4];
    const char* bB = Bb[cb];
    __builtin_amdgcn_s_setprio(1);
#pragma unroll
    for (int ct = 0; ct < 4; ++ct) {
      short8x bf0 = *(const short8x*)(bB + swz(ct * 16 + col16, rg * 16));
      short8x bf1 = *(const short8x*)(bB + swz(ct * 16 + col16, 64 + rg * 16));
      f32x4 tacc = __builtin_amdgcn_mfma_f32_16x16x32_bf16(af0, bf0, z4, 0, 0, 0);
      accS[ct] = __builtin_amdgcn_mfma_f32_16x16x32_bf16(af1, bf1, tacc, 0, 0, 0);
    }
    __builtin_amdgcn_s_setprio(0);

    // ---- write staged B -> nb (other buffer; no race with cb readers) ----
    if (t < 15) {
      short8x v;
      v[0]=(short)f2bf(pb[0].x); v[1]=(short)f2bf(pb[0].y); v[2]=(short)f2bf(pb[0].z); v[3]=(short)f2bf(pb[0].w);
      v[4]=(short)f2bf(pb[1].x); v[5]=(short)f2bf(pb[1].y); v[6]=(short)f2bf(pb[1].z); v[7]=(short)f2bf(pb[1].w);
      *(short8x*)(Bb[nb] + swz(browA, bqA * 32)) = v;
      v[0]=(short)f2bf(pb[2].x); v[1]=(short)f2bf(pb[2].y); v[2]=(short)f2bf(pb[2].z); v[3]=(short)f2bf(pb[2].w);
      v[4]=(short)f2bf(pb[3].x); v[5]=(short)f2bf(pb[3].y); v[6]=(short)f2bf(pb[3].z); v[7]=(short)f2bf(pb[3].w);
      *(short8x*)(Bb[nb] + swz(browA, bqA * 32 + 16)) = v;
    }

    // ---- VT prefetch (issue; consumed after AV — hidden under epilogue+AV) ----
    float4 pv[4];
    if (t < 15) {
      const float* s = vbase + (size_t)((t + 1) * 64 + vsb * 4) * RS + vdb * 4;
#pragma unroll
      for (int k = 0; k < 4; ++k) pv[k] = *(const float4*)(s + (size_t)k * RS);
    }

    // ---- epilogue: bias, exp2, rowsum, rel-V buckets, E -> own-wave LDS ----
    if (!band) {
      const bool right = rel0 > 0;
#pragma unroll
      for (int ct = 0; ct < 4; ++ct) {
#pragma unroll
        for (int r = 0; r < 4; ++r) {
          float bias = mode ? biasf[ct] : biasf[r];
          float e = __builtin_exp2f(accS[ct][r] + bias);
          rowsum[r] += e;
          if (right) wr[r] += e; else wl[r] += e;
          *(short*)(ea + swz(rg * 4 + r, (ct * 16 + col16) * 2)) = (short)f2bf(e);
        }
      }
    } else {
#pragma unroll
      for (int ct = 0; ct < 4; ++ct) {
#pragma unroll
        for (int r = 0; r < 4; ++r) {
          const int row = wv * 16 + rg * 4 + r;
          const int d = rel0 + ct * 16 + col16 - row;
          float e = __builtin_exp2f(accS[ct][r] + biasb[ct][r]);
          rowsum[r] += e;
          if (d <= -12) wl[r] += e;
          else if (d >= 12) wr[r] += e;
          else W[row * PJ + (d + 12)] = e;   // unique (row,j), j in [1,23]
          *(short*)(ea + swz(rg * 4 + r, (ct * 16 + col16) * 2)) = (short)f2bf(e);
        }
      }
    }

    // ---- wave-local E handoff (EA is per-wave; rule #18 pattern) ----
    __builtin_amdgcn_sched_barrier(0);
    asm volatile("s_waitcnt lgkmcnt(0)" ::: "memory");
    __builtin_amdgcn_sched_barrier(0);

    // ---- AV: O += E·V ----
    const char* vB = Vb[cb];
    short8x ef0 = *(const short8x*)(ea + swz(col16, rg * 16));
    short8x ef1 = *(const short8x*)(ea + swz(col16, 64 + rg * 16));
    __builtin_amdgcn_s_setprio(1);
#pragma unroll
    for (int dt = 0; dt < 4; ++dt) {
      short8x v0 = *(const short8x*)(vB + swzVT(dt * 16 + col16, rg * 16));
      short8x v1 = *(const short8x*)(vB + swzVT(dt * 16 + col16, 64 + rg * 16));
      f32x4 tacc = __builtin_amdgcn_mfma_f32_16x16x32_bf16(ef0, v0, accO[dt], 0, 0, 0);
      accO[dt] = __builtin_amdgcn_mfma_f32_16x16x32_bf16(ef1, v1, tacc, 0, 0, 0);
    }
    __builtin_amdgcn_s_setprio(0);

    // ---- write staged VT -> nb ----
    if (t < 15) {
      short4x w4;
      w4[0]=(short)f2bf(pv[0].x); w4[1]=(short)f2bf(pv[1].x); w4[2]=(short)f2bf(pv[2].x); w4[3]=(short)f2bf(pv[3].x);
      *(short4x*)(Vb[nb] + swzVT(vdb * 4 + 0, vsb * 8)) = w4;
      w4[0]=(short)f2bf(pv[0].y); w4[1]=(short)f2bf(pv[1].y); w4[2]=(short)f2bf(pv[2].y); w4[3]=(short)f2bf(pv[3].y);
      *(short4x*)(Vb[nb] + swzVT(vdb * 4 + 1, vsb * 8)) = w4;
      w4[0]=(short)f2bf(pv[0].z); w4[1]=(short)f2bf(pv[1].z); w4[2]=(short)f2bf(pv[2].z); w4[3]=(short)f2bf(pv[3].z);
      *(short4x*)(Vb[nb] + swzVT(vdb * 4 + 2, vsb * 8)) = w4;
      w4[0]=(short)f2bf(pv[0].w); w4[1]=(short)f2bf(pv[1].w); w4[2]=(short)f2bf(pv[2].w); w4[3]=(short)f2bf(pv[3].w);
      *(short4x*)(Vb[nb] + swzVT(vdb * 4 + 3, vsb * 8)) = w4;
    }
    __syncthreads();  // single barrier per step
  }

  // ---- tab into U (E region dead now) ----
  float* tabf = (float*)U;
  for (int i = tid; i < 25 * 64; i += 256) tabf[i] = tb[i];
  __syncthreads();

  // ---- reduce stats, rel-V, normalize, store ----
#pragma unroll
  for (int r = 0; r < 4; ++r) {
#pragma unroll
    for (int m = 1; m < 16; m <<= 1) {
      rowsum[r] += __shfl_xor(rowsum[r], m);
      wl[r] += __shfl_xor(wl[r], m);
      wr[r] += __shfl_xor(wr[r], m);
    }
  }
  float inv[4];
#pragma unroll
  for (int r = 0; r < 4; ++r) inv[r] = 1.f / rowsum[r];

#pragma unroll
  for (int dt = 0; dt < 4; ++dt) {
#pragma unroll
    for (int r = 0; r < 4; ++r) {
      const int row = wv * 16 + rg * 4 + r;
      const int dd = dt * 16 + col16;
      float vr = wl[r] * tabf[dd] + wr[r] * tabf[24 * 64 + dd];
#pragma unroll
      for (int j = 1; j < 24; ++j) vr += W[row * PJ + j] * tabf[j * 64 + dd];
      outb[(size_t)(l0 + row) * RS + dd] = (accO[dt][r] + vr) * inv[r];
    }
  }
}

extern "C" void kernel_launch(void* const* d_in, const int* in_sizes, int n_in,
                              void* d_out, int out_size, void* d_ws, size_t ws_size,
                              hipStream_t stream) {
  const float* x = (const float*)d_in[0];
  const float* y = (const float*)d_in[1];
  const float* vx = (const float*)d_in[2];
  const float* vy = (const float*)d_in[3];
  const float* relk = (const float*)d_in[4];
  const float* relvx = (const float*)d_in[5];
  const float* relvy = (const float*)d_in[6];
  float* out = (float*)d_out;

  float* P = (float*)d_ws;  // [32][1024][PJ] f32 = 3.4 MB

  k_relproj<<<dim3(16, NP), 256, 0, stream>>>(x, relk, P);
  k_fused<<<dim3(1024), 256, 0, stream>>>(x, y, vx, vy, relvx, relvy, P, out);
}